// Round 3
// baseline (127.016 us; speedup 1.0000x reference)
//
#include <hip/hip_runtime.h>
#include <math.h>

// Problem constants
#define BATCH 2
#define NTOK  2048
#define FIN   256
#define HEADS 8
#define FOUT  32
#define BH    (BATCH*HEADS)    // 16
#define NCOL  (HEADS*FOUT)     // 256
#define ROWS  (BATCH*NTOK)     // 4096

// ---------------------------------------------------------------------------
// Workspace layout (float offsets). Partial ranks alias V1 (consumed by
// k_scatter before k_vscan overwrites V1 — safe on one stream).
// ---------------------------------------------------------------------------
static const size_t OFF_E1   = 1048576;                 // e1  [16][2048]
static const size_t OFF_E2   = OFF_E1 + 32768;          // e2  [16][2048]
static const size_t OFF_SKEY = OFF_E2 + 32768;          // skey[16][2048]
static const size_t OFF_SIDX = OFF_SKEY + 32768;        // sidx[16][2048] int
static const size_t OFF_S1   = OFF_SIDX + 32768;        // S1  [16][2049]
static const size_t OFF_P2   = OFF_S1 + 32784;          // P2  [16][2049]
static const size_t OFF_V1   = OFF_P2 + 32784;          // V1  [16][2049][32]
static const size_t OFF_P2V  = OFF_V1 + 16u*2049u*32u;  // P2V [16][2049][32]
static const size_t OFF_PART = OFF_V1;                  // partial[8][16][2048] int

// ---------------------------------------------------------------------------
// K1: Wh = h @ W (4096x256 @ 256x256 fp32) + fused e1/e2 epilogue.
// Tile 64x64, BK=64, block 256 (16 tc x 16 tr), thread = 4 rows x 4 cols.
// A staged TRANSPOSED (At[k][row]) so per k: 1 b128 A + 1 b128 B for 16 FMA
// -> FMA-bound (~32 cyc FMA vs 24 cyc LDS per k).
// Epilogue: 64-col tile = heads {2by, 2by+1} complete; dot acc rows with
// a1/a2 slice, shfl_xor-reduce over 8 tc lanes, tc==0 / tc==8 write e1/e2.
// ---------------------------------------------------------------------------
__global__ __launch_bounds__(256) void k_gemm(const float* __restrict__ h,
                                              const float* __restrict__ W,
                                              const float* __restrict__ a,
                                              float* __restrict__ Wh,
                                              float* __restrict__ e1,
                                              float* __restrict__ e2) {
    __shared__ float At[64 * 68];   // [k][row], row-major stride 68
    __shared__ float Bs[64 * 68];   // [k][col], stride 68
    __shared__ float av[64];
    const int tid  = threadIdx.x;
    const int row0 = blockIdx.x * 64;
    const int col0 = blockIdx.y * 64;
    const int tc = tid & 15;        // col group (float4)
    const int tr = tid >> 4;        // row group (4 rows)
    const int r0 = tr * 4;
    const int c0 = tc * 4;
    if (tid < 64) av[tid] = a[tid];

    const float4* h4 = (const float4*)h;   // [4096][64]
    const float4* W4 = (const float4*)W;   // [256][64]

    float4 acc[4];
    #pragma unroll
    for (int i = 0; i < 4; ++i) acc[i] = make_float4(0.f,0.f,0.f,0.f);

    for (int kc = 0; kc < FIN; kc += 64) {
        // stage A transposed: 64 rows x 16 f4; thread loads 4 f4 (coalesced)
        #pragma unroll
        for (int q = 0; q < 4; ++q) {
            int idx = q * 256 + tid;
            int r  = idx >> 4;          // 0..63
            int kq = idx & 15;          // f4 within chunk
            float4 v = h4[(size_t)(row0 + r) * 64 + (kc >> 2) + kq];
            At[(kq * 4 + 0) * 68 + r] = v.x;
            At[(kq * 4 + 1) * 68 + r] = v.y;
            At[(kq * 4 + 2) * 68 + r] = v.z;
            At[(kq * 4 + 3) * 68 + r] = v.w;
        }
        // stage B: 64 k x 16 f4 (coalesced, contiguous LDS writes)
        #pragma unroll
        for (int q = 0; q < 4; ++q) {
            int idx = q * 256 + tid;
            int kr = idx >> 4;
            int cf = idx & 15;
            float4 v = W4[(size_t)(kc + kr) * 64 + (col0 >> 2) + cf];
            *(float4*)&Bs[kr * 68 + cf * 4] = v;
        }
        __syncthreads();

        #pragma unroll 4
        for (int k = 0; k < 64; ++k) {
            float4 a4 = *(const float4*)&At[k * 68 + r0];
            float4 b4 = *(const float4*)&Bs[k * 68 + c0];
            acc[0].x += a4.x * b4.x; acc[0].y += a4.x * b4.y; acc[0].z += a4.x * b4.z; acc[0].w += a4.x * b4.w;
            acc[1].x += a4.y * b4.x; acc[1].y += a4.y * b4.y; acc[1].z += a4.y * b4.z; acc[1].w += a4.y * b4.w;
            acc[2].x += a4.z * b4.x; acc[2].y += a4.z * b4.y; acc[2].z += a4.z * b4.z; acc[2].w += a4.z * b4.w;
            acc[3].x += a4.w * b4.x; acc[3].y += a4.w * b4.y; acc[3].z += a4.w * b4.z; acc[3].w += a4.w * b4.w;
        }
        __syncthreads();
    }

    // store Wh
    #pragma unroll
    for (int i = 0; i < 4; ++i)
        *(float4*)(Wh + (size_t)(row0 + r0 + i) * NCOL + col0 + c0) = acc[i];

    // fused e1/e2: f-index within head = (tc*4+c) & 31
    const int f0 = c0 & 31;
    float s1[4], s2[4];
    #pragma unroll
    for (int i = 0; i < 4; ++i) {
        s1[i] = acc[i].x * av[f0+0] + acc[i].y * av[f0+1] + acc[i].z * av[f0+2] + acc[i].w * av[f0+3];
        s2[i] = acc[i].x * av[32+f0+0] + acc[i].y * av[32+f0+1] + acc[i].z * av[32+f0+2] + acc[i].w * av[32+f0+3];
    }
    // reduce over the 8 tc-lanes of each head (tc bits 0..2; bit 3 = head parity)
    #pragma unroll
    for (int m = 1; m < 8; m <<= 1) {
        #pragma unroll
        for (int i = 0; i < 4; ++i) {
            s1[i] += __shfl_xor(s1[i], m, 64);
            s2[i] += __shfl_xor(s2[i], m, 64);
        }
    }
    if ((tc & 7) == 0) {
        const int hh = (col0 >> 5) + (tc >> 3);   // head index 0..7
        #pragma unroll
        for (int i = 0; i < 4; ++i) {
            int grow = row0 + r0 + i;
            int b = grow >> 11;
            int n = grow & (NTOK - 1);
            e1[(b * HEADS + hh) * NTOK + n] = s1[i];
            e2[(b * HEADS + hh) * NTOK + n] = s2[i];
        }
    }
}

// ---------------------------------------------------------------------------
// K2a: partial descending ranks. grid (16 bh, 8 jtile, 8 ktile), block 256.
// ---------------------------------------------------------------------------
__global__ __launch_bounds__(256) void k_rank8(const float* __restrict__ e2g,
                                               int* __restrict__ partial) {
    __shared__ float ch[256];
    const int tid = threadIdx.x;
    const int bh  = blockIdx.x;
    const int jt  = blockIdx.y;
    const int kt  = blockIdx.z;
    ch[tid] = e2g[bh * NTOK + kt * 256 + tid];
    __syncthreads();

    const int j    = jt * 256 + tid;
    const float my = e2g[bh * NTOK + j];
    const int base0 = kt * 256;
    int rank = 0;
    const float4* c4 = (const float4*)ch;
    #pragma unroll 8
    for (int q = 0; q < 64; ++q) {
        float4 v = c4[q];
        int bb = base0 + q * 4;
        rank += (v.x > my) || ((v.x == my) && (bb + 0 < j));
        rank += (v.y > my) || ((v.y == my) && (bb + 1 < j));
        rank += (v.z > my) || ((v.z == my) && (bb + 2 < j));
        rank += (v.w > my) || ((v.w == my) && (bb + 3 < j));
    }
    partial[(kt * BH + bh) * NTOK + j] = rank;
}

// ---------------------------------------------------------------------------
// K2b: sum 8 partials -> rank; scatter key + original index.
// ---------------------------------------------------------------------------
__global__ __launch_bounds__(256) void k_scatter(const float* __restrict__ e2g,
                                                 const int* __restrict__ partial,
                                                 float* __restrict__ skey,
                                                 int* __restrict__ sidx) {
    const int tid = threadIdx.x;
    const int bh  = blockIdx.x;
    const int jt  = blockIdx.y;
    const int j   = jt * 256 + tid;
    int rank = 0;
    #pragma unroll
    for (int kt = 0; kt < 8; ++kt)
        rank += partial[(kt * BH + bh) * NTOK + j];
    skey[bh * NTOK + rank] = e2g[bh * NTOK + j];
    sidx[bh * NTOK + rank] = j;
}

// ---------------------------------------------------------------------------
// K3: work-efficient scans; exp computed inline from sorted skey.
// grid (9 fg, 16 bh, 2 z), block 1024; thread owns j=2t,2t+1.
// fg<8 : float4 scan of w*Wh -> V1 (z=0) / P2V (z=1)
// fg==8: scalar scan of w    -> S1 (z=0) / P2  (z=1)
// Writes exclusive form dst[k]=incl[k-1], dst[0]=0, dst[2048]=total.
// ---------------------------------------------------------------------------
__global__ __launch_bounds__(1024) void k_vscan(const float* __restrict__ Wh,
                                                const int* __restrict__ sidx,
                                                const float* __restrict__ skey,
                                                float* __restrict__ V1,
                                                float* __restrict__ P2V,
                                                float* __restrict__ S1,
                                                float* __restrict__ P2) {
    __shared__ float4 wtot[16];
    __shared__ float4 woff[16];
    const int t    = threadIdx.x;
    const int lane = t & 63;
    const int wv   = t >> 6;
    const int fg   = blockIdx.x;
    const int bh   = blockIdx.y;
    const int z    = blockIdx.z;
    const int b    = bh >> 3;
    const int hh   = bh & 7;
    const float scale = z ? 0.01f : 1.0f;

    const int j0 = 2 * t;
    const float w0 = expf(scale * skey[bh * NTOK + j0]);
    const float w1 = expf(scale * skey[bh * NTOK + j0 + 1]);
    float4 v0, v1;
    if (fg < 8) {
        int sj0 = sidx[bh * NTOK + j0];
        int sj1 = sidx[bh * NTOK + j0 + 1];
        float4 g0 = *(const float4*)(Wh + (size_t)(b * NTOK + sj0) * NCOL + hh * FOUT + fg * 4);
        float4 g1 = *(const float4*)(Wh + (size_t)(b * NTOK + sj1) * NCOL + hh * FOUT + fg * 4);
        v0 = make_float4(w0 * g0.x, w0 * g0.y, w0 * g0.z, w0 * g0.w);
        v1 = make_float4(w1 * g1.x, w1 * g1.y, w1 * g1.z, w1 * g1.w);
    } else {
        v0 = make_float4(w0, 0.f, 0.f, 0.f);
        v1 = make_float4(w1, 0.f, 0.f, 0.f);
    }

    float4 s = make_float4(v0.x + v1.x, v0.y + v1.y, v0.z + v1.z, v0.w + v1.w);
    #pragma unroll
    for (int d = 1; d < 64; d <<= 1) {
        float ux = __shfl_up(s.x, (unsigned)d, 64);
        float uy = __shfl_up(s.y, (unsigned)d, 64);
        float uz = __shfl_up(s.z, (unsigned)d, 64);
        float uw = __shfl_up(s.w, (unsigned)d, 64);
        if (lane >= d) { s.x += ux; s.y += uy; s.z += uz; s.w += uw; }
    }
    float4 pair = make_float4(v0.x + v1.x, v0.y + v1.y, v0.z + v1.z, v0.w + v1.w);
    float4 excl = make_float4(s.x - pair.x, s.y - pair.y, s.z - pair.z, s.w - pair.w);
    if (lane == 63) wtot[wv] = s;
    __syncthreads();
    if (t < 16) {
        float4 ws = wtot[t];
        float4 inc = ws;
        #pragma unroll
        for (int d = 1; d < 16; d <<= 1) {
            float ux = __shfl_up(inc.x, (unsigned)d, 16);
            float uy = __shfl_up(inc.y, (unsigned)d, 16);
            float uz = __shfl_up(inc.z, (unsigned)d, 16);
            float uw = __shfl_up(inc.w, (unsigned)d, 16);
            if ((t & 15) >= d) { inc.x += ux; inc.y += uy; inc.z += uz; inc.w += uw; }
        }
        woff[t] = make_float4(inc.x - ws.x, inc.y - ws.y, inc.z - ws.z, inc.w - ws.w);
    }
    __syncthreads();

    float4 base = woff[wv];
    float4 i0 = make_float4(base.x + excl.x + v0.x, base.y + excl.y + v0.y,
                            base.z + excl.z + v0.z, base.w + excl.w + v0.w);
    float4 i1 = make_float4(i0.x + v1.x, i0.y + v1.y, i0.z + v1.z, i0.w + v1.w);

    if (fg < 8) {
        float* dst = z ? P2V : V1;
        *(float4*)(dst + ((size_t)bh * 2049 + (j0 + 1)) * 32 + fg * 4) = i0;
        *(float4*)(dst + ((size_t)bh * 2049 + (j0 + 2)) * 32 + fg * 4) = i1;
        if (t == 0)
            *(float4*)(dst + ((size_t)bh * 2049) * 32 + fg * 4) = make_float4(0.f,0.f,0.f,0.f);
    } else {
        float* dst = z ? P2 : S1;
        dst[bh * 2049 + j0 + 1] = i0.x;
        dst[bh * 2049 + j0 + 2] = i1.x;
        if (t == 0) dst[bh * 2049] = 0.f;
    }
}

// ---------------------------------------------------------------------------
// K4: per (b,h,i): binary-search k_i, combine prefix sums, write output.
// grid (64 itile, 16 bh), block 256 = 32 i x 8 fg
// ---------------------------------------------------------------------------
__global__ __launch_bounds__(256) void k_out(const float* __restrict__ skey,
                                             const float* __restrict__ e1g,
                                             const float* __restrict__ S1,
                                             const float* __restrict__ P2,
                                             const float* __restrict__ V1,
                                             const float* __restrict__ P2V,
                                             float* __restrict__ out) {
    __shared__ float keys[NTOK];
    const int tid = threadIdx.x;
    const int it  = blockIdx.x;
    const int bh  = blockIdx.y;
    const int b   = bh >> 3;
    const int hh  = bh & 7;
    #pragma unroll
    for (int q = 0; q < 8; ++q)
        keys[q * 256 + tid] = skey[bh * NTOK + q * 256 + tid];
    __syncthreads();

    const int i  = it * 32 + (tid >> 3);
    const int fg = tid & 7;
    const float e1v = e1g[bh * NTOK + i];
    const float th  = -e1v;
    int lo = 0, hi = NTOK;
    while (lo < hi) {
        int mid = (lo + hi) >> 1;
        if (keys[mid] > th) lo = mid + 1; else hi = mid;
    }
    const int k = lo;
    const float A = expf(e1v);
    const float C = expf(0.01f * e1v);
    const float s1  = S1[bh * 2049 + k];
    const float p2k = P2[bh * 2049 + k];
    const float p2t = P2[bh * 2049 + 2048];
    const float l   = A * s1 + C * (p2t - p2k);
    const float inv = 1.0f / l;
    float4 v1   = *(const float4*)(V1  + ((size_t)bh * 2049 + k)    * 32 + fg * 4);
    float4 p2v  = *(const float4*)(P2V + ((size_t)bh * 2049 + k)    * 32 + fg * 4);
    float4 p2vt = *(const float4*)(P2V + ((size_t)bh * 2049 + 2048) * 32 + fg * 4);
    float4 o;
    o.x = (A * v1.x + C * (p2vt.x - p2v.x)) * inv;
    o.y = (A * v1.y + C * (p2vt.y - p2v.y)) * inv;
    o.z = (A * v1.z + C * (p2vt.z - p2v.z)) * inv;
    o.w = (A * v1.w + C * (p2vt.w - p2v.w)) * inv;
    *(float4*)(out + (size_t)(b * NTOK + i) * NCOL + hh * FOUT + fg * 4) = o;
}

// ---------------------------------------------------------------------------
extern "C" void kernel_launch(void* const* d_in, const int* in_sizes, int n_in,
                              void* d_out, int out_size, void* d_ws, size_t ws_size,
                              hipStream_t stream) {
    const float* h = (const float*)d_in[0];
    // d_in[1] = adj — unused by the reference computation
    const float* W = (const float*)d_in[2];
    const float* a = (const float*)d_in[3];
    float* out = (float*)d_out;
    float* ws  = (float*)d_ws;

    float* Wh   = ws;
    float* e1   = ws + OFF_E1;
    float* e2   = ws + OFF_E2;
    float* skey = ws + OFF_SKEY;
    int*   sidx = (int*)(ws + OFF_SIDX);
    float* S1   = ws + OFF_S1;
    float* P2   = ws + OFF_P2;
    float* V1   = ws + OFF_V1;
    float* P2V  = ws + OFF_P2V;
    int*   part = (int*)(ws + OFF_PART);   // aliases V1 (consumed before vscan)

    k_gemm   <<<dim3(ROWS / 64, NCOL / 64), 256, 0, stream>>>(h, W, a, Wh, e1, e2);
    k_rank8  <<<dim3(BH, 8, 8),             256, 0, stream>>>(e2, part);
    k_scatter<<<dim3(BH, 8),                256, 0, stream>>>(e2, part, skey, sidx);
    k_vscan  <<<dim3(9, BH, 2),            1024, 0, stream>>>(Wh, sidx, skey, V1, P2V, S1, P2);
    k_out    <<<dim3(NTOK / 32, BH),        256, 0, stream>>>(skey, e1, S1, P2, V1, P2V, out);
}